// Round 5
// baseline (6498.875 us; speedup 1.0000x reference)
//
#include <hip/hip_runtime.h>

typedef unsigned short u16;
typedef __attribute__((ext_vector_type(8))) short short8;

#define NSYM 512

// ---------------------------------------------------------------------------
// Build u16 copies of the luts + fused relu(add_lut) table
// ---------------------------------------------------------------------------
__global__ void build_tables_kernel(const int* __restrict__ conv_i,
                                    const int* __restrict__ add_i,
                                    const int* __restrict__ relu_i,
                                    u16* __restrict__ conv_u,
                                    u16* __restrict__ add_u,
                                    u16* __restrict__ addrelu_u) {
    int i = blockIdx.x * blockDim.x + threadIdx.x;
    if (i < NSYM * NSYM) {
        conv_u[i] = (u16)conv_i[i];
        int a = add_i[i];
        add_u[i] = (u16)a;
        addrelu_u[i] = (u16)relu_i[a];
    }
}

// ---------------------------------------------------------------------------
// Quantize: argmin over sorted centroids == binary search + neighbor compare.
// ---------------------------------------------------------------------------
__global__ void quantize_kernel(const float* __restrict__ x,
                                u16* __restrict__ s0,
                                const float* __restrict__ cent,
                                int n) {
    __shared__ float c[NSYM];
    for (int t = threadIdx.x; t < NSYM; t += blockDim.x) c[t] = cent[t];
    __syncthreads();
    int i = blockIdx.x * blockDim.x + threadIdx.x;
    if (i >= n) return;
    int ch = i % 3; int t2 = i / 3; int xx = t2 % 67; int t3 = t2 / 67;
    int y = t3 % 67; int img = t3 / 67;
    float v = x[((img * 3 + ch) * 67 + y) * 67 + xx];
    int lo = 0, hi = NSYM;
    while (lo < hi) { int mid = (lo + hi) >> 1; if (c[mid] < v) lo = mid + 1; else hi = mid; }
    int idx;
    if (lo == 0) idx = 0;
    else if (lo == NSYM) idx = NSYM - 1;
    else {
        float d1 = v - c[lo - 1];
        float d2 = v - c[lo];
        idx = (d1 * d1 <= d2 * d2) ? (lo - 1) : lo;
    }
    s0[i] = (u16)idx;
}

// ---------------------------------------------------------------------------
// Symbolic conv layer, producer/consumer wave pair per block.
//   block = 128 threads = 2 waves; one output pixel x 64 out-channels.
//   wave1 (producer): computes m_j = conv[patch_j, W[j,oc]] for chunk t+1
//                     into LDS (double-buffered), throughput-bound.
//   wave0 (consumer): chains carry = addt[carry, m_j] reading m from LDS;
//                     critical path = one dependent L2 gather per step.
//   m-buffer layout: per-lane row of CH u16, 16B blocks XOR-swizzled by
//   (lane&7) -> ds_read_b128/ds_write_b128 are bank-conflict-free.
// ---------------------------------------------------------------------------
__global__ __launch_bounds__(128) void symconv_kernel(
        const u16* __restrict__ in, u16* __restrict__ out,
        const int* __restrict__ Wl,
        const u16* __restrict__ conv,
        const u16* __restrict__ addt,
        const u16* __restrict__ addlast,
        int H, int Wd, int C, int OC, int nOCG,
        int K, int ST, int PAD, int OH, int OW, int CH) {
    extern __shared__ char lds[];
    int J = K * K * C;
    u16* patch = (u16*)lds;
    int patchBytes = (J * 2 + 127) & ~127;
    char* mbuf0 = lds + patchBytes;
    char* mbuf1 = mbuf0 + CH * 64 * 2;

    int bid = blockIdx.x;
    int ocg = bid % nOCG;
    int pix = bid / nOCG;
    int img = pix / (OH * OW);
    int rem = pix - img * (OH * OW);
    int oy = rem / OW;
    int ox = rem - oy * OW;

    // stage patch (all 128 threads), j order = (kr, kc, c), c fastest
    for (int t = threadIdx.x; t < J; t += 128) {
        int c = t % C; int tt = t / C; int kc = tt % K; int kr = tt / K;
        int iy = oy * ST + kr - PAD;
        int ix = ox * ST + kc - PAD;
        u16 v = 0;  // jnp.pad pads with symbol 0
        if (iy >= 0 && iy < H && ix >= 0 && ix < Wd)
            v = in[((img * H + iy) * Wd + ix) * C + c];
        patch[t] = v;
    }
    __syncthreads();

    int wave = threadIdx.x >> 6;
    int lane = threadIdx.x & 63;
    int oc = ocg * 64 + lane;
    int nch = (J + CH - 1) / CH;
    int rowbase = lane * CH * 2;
    int lsw = lane & 7;

    auto produce = [&](int t) {
        char* dst = (t & 1) ? mbuf1 : mbuf0;
        int j0 = t * CH;
        int n = min(CH, J - j0);
        int nfull = n >> 3, tail = n & 7;
        for (int g = 0; g < nfull; ++g) {
            u16 v[8];
            #pragma unroll
            for (int u = 0; u < 8; ++u) {
                int j = j0 + g * 8 + u;
                int wv = Wl[j * OC + oc];
                v[u] = conv[((int)patch[j] << 9) + wv];
            }
            short8 pk;
            #pragma unroll
            for (int u = 0; u < 8; ++u) pk[u] = (short)v[u];
            *(short8*)(dst + rowbase + ((g ^ lsw) << 4)) = pk;
        }
        for (int u = 0; u < tail; ++u) {
            int j = j0 + nfull * 8 + u;
            int wv = Wl[j * OC + oc];
            u16 vv = conv[((int)patch[j] << 9) + wv];
            *(u16*)(dst + rowbase + ((nfull ^ lsw) << 4) + (u << 1)) = vv;
        }
    };

    int carry = 0;

    auto chain = [&](int t) {
        const char* src = (t & 1) ? mbuf1 : mbuf0;
        int j0 = t * CH;
        int n = min(CH, J - j0);
        bool lastchunk = (j0 + n == J);
        int ncha = n - (lastchunk ? 1 : 0);  // last element of layer uses addlast
        int nfull = ncha >> 3, tail = ncha & 7;
        short8 cur, nxt;
        int g = 0;
        if (nfull > 0) {
            cur = *(const short8*)(src + rowbase + ((0 ^ lsw) << 4));
            if (t == 0) {  // first group of the whole chain: element 0 initializes
                if (nfull > 1) nxt = *(const short8*)(src + rowbase + ((1 ^ lsw) << 4));
                carry = (int)(unsigned short)cur[0];
                #pragma unroll
                for (int u = 1; u < 8; ++u)
                    carry = (int)addt[(carry << 9) + (int)(unsigned short)cur[u]];
                cur = nxt;
                g = 1;
            }
        }
        for (; g < nfull; ++g) {
            if (g + 1 < nfull)
                nxt = *(const short8*)(src + rowbase + (((g + 1) ^ lsw) << 4));
            #pragma unroll
            for (int u = 0; u < 8; ++u)
                carry = (int)addt[(carry << 9) + (int)(unsigned short)cur[u]];
            cur = nxt;
        }
        for (int u = 0; u < tail; ++u) {
            int jj = nfull * 8 + u;
            int m = (int)*(const u16*)(src + rowbase + (((jj >> 3) ^ lsw) << 4) + ((jj & 7) << 1));
            if (t == 0 && jj == 0) carry = m;
            else carry = (int)addt[(carry << 9) + m];
        }
        if (lastchunk) {
            int jj = n - 1;
            int m = (int)*(const u16*)(src + rowbase + (((jj >> 3) ^ lsw) << 4) + ((jj & 7) << 1));
            carry = (int)addlast[(carry << 9) + m];
        }
    };

    if (wave == 1) produce(0);
    __syncthreads();
    for (int t = 0; t < nch; ++t) {
        if (wave == 1) {
            if (t + 1 < nch) produce(t + 1);
        } else {
            chain(t);
        }
        __syncthreads();
    }
    if (wave == 0) out[pix * OC + oc] = (u16)carry;
}

// ---------------------------------------------------------------------------
// Head: vals = centroid[s]; feats = mean over 2x2; out = feats @ fc_w.T + fc_b
// ---------------------------------------------------------------------------
__global__ void head_kernel(const u16* __restrict__ s,
                            const float* __restrict__ cent,
                            const float* __restrict__ fcw,
                            const float* __restrict__ fcb,
                            float* __restrict__ out) {
    __shared__ float feats[NSYM];
    int img = blockIdx.x;
    const u16* sp = s + img * 4 * NSYM;
    for (int c = threadIdx.x; c < NSYM; c += blockDim.x) {
        float acc = cent[sp[c]] + cent[sp[NSYM + c]] +
                    cent[sp[2 * NSYM + c]] + cent[sp[3 * NSYM + c]];
        feats[c] = acc * 0.25f;
    }
    __syncthreads();
    int o = blockIdx.y * blockDim.x + threadIdx.x;
    if (o < 1000) {
        float acc = fcb[o];
        const float* wr = fcw + o * NSYM;
        for (int c2 = 0; c2 < NSYM; ++c2) acc += feats[c2] * wr[c2];
        out[img * 1000 + o] = acc;
    }
}

// ---------------------------------------------------------------------------
extern "C" void kernel_launch(void* const* d_in, const int* in_sizes, int n_in,
                              void* d_out, int out_size, void* d_ws, size_t ws_size,
                              hipStream_t stream) {
    const float* x = (const float*)d_in[0];
    const int* w[17];
    for (int i = 0; i < 17; ++i) w[i] = (const int*)d_in[1 + i];
    const int* conv_i = (const int*)d_in[18];
    const int* add_i  = (const int*)d_in[19];
    const int* relu_i = (const int*)d_in[20];
    const float* cent = (const float*)d_in[21];
    const float* fcw  = (const float*)d_in[22];
    const float* fcb  = (const float*)d_in[23];
    float* out = (float*)d_out;

    char* p = (char*)d_ws;
    u16* conv_u    = (u16*)p; p += NSYM * NSYM * 2;
    u16* add_u     = (u16*)p; p += NSYM * NSYM * 2;
    u16* addrelu_u = (u16*)p; p += NSYM * NSYM * 2;
    u16* act0      = (u16*)p; p += ((8 * 67 * 67 * 3 * 2 + 255) / 256) * 256;
    u16* actA      = (u16*)p; p += 8 * 16 * 16 * 64 * 2;
    u16* actB      = (u16*)p; p += 8 * 16 * 16 * 64 * 2;

    build_tables_kernel<<<(NSYM * NSYM + 255) / 256, 256, 0, stream>>>(
        conv_i, add_i, relu_i, conv_u, add_u, addrelu_u);

    int nq = 8 * 67 * 67 * 3;
    quantize_kernel<<<(nq + 255) / 256, 256, 0, stream>>>(x, act0, cent, nq);

    struct LC { int K, ST, PAD, C, OC, H, OH, relu; };
    static const LC L[17] = {
        {7,4,0,  3, 64,67,16,1},
        {3,1,1, 64, 64,16,16,1},
        {3,1,1, 64, 64,16,16,0},
        {3,1,1, 64, 64,16,16,1},
        {3,1,1, 64, 64,16,16,0},
        {3,2,1, 64,128,16, 8,1},
        {3,1,1,128,128, 8, 8,0},
        {3,1,1,128,128, 8, 8,1},
        {3,1,1,128,128, 8, 8,0},
        {3,2,1,128,256, 8, 4,1},
        {3,1,1,256,256, 4, 4,0},
        {3,1,1,256,256, 4, 4,1},
        {3,1,1,256,256, 4, 4,0},
        {3,2,1,256,512, 4, 2,1},
        {3,1,1,512,512, 2, 2,0},
        {3,1,1,512,512, 2, 2,1},
        {3,1,1,512,512, 2, 2,0},
    };
    // chunk size per layer: LDS = patchBytes + CH*256 stays <= 64KB and
    // preserves multi-block residency on wide layers (8/4/3-2 blocks per CU).
    static const int CHs[17] = {64, 64,64,64,64, 128, 128,128,128,
                                192, 192,192,192, 192, 192,192,192};

    const u16* cur = act0;
    u16* nxt = actA;
    for (int i = 0; i < 17; ++i) {
        int OH = L[i].OH, OW = L[i].OH;
        int nOCG = L[i].OC / 64;
        int grid = 8 * OH * OW * nOCG;
        int J = L[i].K * L[i].K * L[i].C;
        int CH = CHs[i];
        int patchBytes = (J * 2 + 127) & ~127;
        int ldsBytes = patchBytes + CH * 256;
        symconv_kernel<<<grid, 128, ldsBytes, stream>>>(
            cur, nxt, w[i], conv_u, add_u, L[i].relu ? addrelu_u : add_u,
            L[i].H, L[i].H, L[i].C, L[i].OC, nOCG,
            L[i].K, L[i].ST, L[i].PAD, OH, OW, CH);
        cur = nxt;
        nxt = (nxt == actA) ? actB : actA;
    }

    head_kernel<<<dim3(8, 4), 256, 0, stream>>>(cur, cent, fcw, fcb, out);
}